// Round 9
// baseline (302.770 us; speedup 1.0000x reference)
//
#include <hip/hip_runtime.h>
#include <hip/hip_fp16.h>

// MPA_16698832847132 — round 9: re-fused conv at 2 blocks/CU.
//  conv_fused2: no inA staging (conv1 A-fragments read coalesced from global,
//  L1/L2-resident across taps), LDS = yB(74K)+wH2+stats = 80,256 B -> 2 blocks/CU.
//  Kills round-8's 152MB y1 round-trip AND round-6/7's 1-block/CU latency wall.
// Workspace: qkv bf16 @0 (25,165,824) | w f32 @25,165,824 (33,554,432) | oh f32 @58,720,256

typedef __attribute__((ext_vector_type(8))) short bf16x8;
typedef __attribute__((ext_vector_type(8))) _Float16 f16x8;
typedef __attribute__((ext_vector_type(4))) float f32x4;

__device__ __forceinline__ unsigned short f2bf(float f) {
  unsigned u = __builtin_bit_cast(unsigned, f);
  u += 0x7FFFu + ((u >> 16) & 1u);
  return (unsigned short)(u >> 16);
}

// ---------------- C[M][N] = A[M][K] * B[N][K]^T (+bias), f16 MFMA --------------
template<bool OUT_BF16>
__global__ __launch_bounds__(256) void gemm_f16_bt(
    const float* __restrict__ A, const float* __restrict__ B,
    void* __restrict__ Cv, const float* __restrict__ bias,
    int M, int N, int K)
{
  __shared__ __align__(16) _Float16 As[128 * 40];
  __shared__ __align__(16) _Float16 Bs[128 * 40];
  const int tid = threadIdx.x;
  const int wv = tid >> 6, ln = tid & 63, lr = ln & 15, lq = ln >> 4;
  const int wm = wv >> 1, wn = wv & 1;
  const int m0 = blockIdx.y * 128, n0 = blockIdx.x * 128;

  f32x4 acc[4][4];
#pragma unroll
  for (int i = 0; i < 4; i++)
#pragma unroll
    for (int j = 0; j < 4; j++) acc[i][j] = (f32x4){0.f, 0.f, 0.f, 0.f};

  const int sr = tid >> 1, sk = (tid & 1) * 16;
  const float* Ap = A + (size_t)(m0 + sr) * K + sk;
  const float* Bp = B + (size_t)(n0 + sr) * K + sk;

  for (int k0 = 0; k0 < K; k0 += 32) {
    float4 av0 = *(const float4*)(Ap + k0);
    float4 av1 = *(const float4*)(Ap + k0 + 4);
    float4 av2 = *(const float4*)(Ap + k0 + 8);
    float4 av3 = *(const float4*)(Ap + k0 + 12);
    float4 bv0 = *(const float4*)(Bp + k0);
    float4 bv1 = *(const float4*)(Bp + k0 + 4);
    float4 bv2 = *(const float4*)(Bp + k0 + 8);
    float4 bv3 = *(const float4*)(Bp + k0 + 12);
    __syncthreads();
    {
      f16x8 p0, p1, r0, r1;
      p0[0]=(_Float16)av0.x; p0[1]=(_Float16)av0.y; p0[2]=(_Float16)av0.z; p0[3]=(_Float16)av0.w;
      p0[4]=(_Float16)av1.x; p0[5]=(_Float16)av1.y; p0[6]=(_Float16)av1.z; p0[7]=(_Float16)av1.w;
      p1[0]=(_Float16)av2.x; p1[1]=(_Float16)av2.y; p1[2]=(_Float16)av2.z; p1[3]=(_Float16)av2.w;
      p1[4]=(_Float16)av3.x; p1[5]=(_Float16)av3.y; p1[6]=(_Float16)av3.z; p1[7]=(_Float16)av3.w;
      r0[0]=(_Float16)bv0.x; r0[1]=(_Float16)bv0.y; r0[2]=(_Float16)bv0.z; r0[3]=(_Float16)bv0.w;
      r0[4]=(_Float16)bv1.x; r0[5]=(_Float16)bv1.y; r0[6]=(_Float16)bv1.z; r0[7]=(_Float16)bv1.w;
      r1[0]=(_Float16)bv2.x; r1[1]=(_Float16)bv2.y; r1[2]=(_Float16)bv2.z; r1[3]=(_Float16)bv2.w;
      r1[4]=(_Float16)bv3.x; r1[5]=(_Float16)bv3.y; r1[6]=(_Float16)bv3.z; r1[7]=(_Float16)bv3.w;
      *(f16x8*)&As[sr * 40 + sk] = p0;
      *(f16x8*)&As[sr * 40 + sk + 8] = p1;
      *(f16x8*)&Bs[sr * 40 + sk] = r0;
      *(f16x8*)&Bs[sr * 40 + sk + 8] = r1;
    }
    __syncthreads();
    f16x8 af[4], bf[4];
#pragma unroll
    for (int mf = 0; mf < 4; mf++)
      af[mf] = *(const f16x8*)&As[(wm * 64 + mf * 16 + lr) * 40 + lq * 8];
#pragma unroll
    for (int nf = 0; nf < 4; nf++)
      bf[nf] = *(const f16x8*)&Bs[(wn * 64 + nf * 16 + lr) * 40 + lq * 8];
#pragma unroll
    for (int mf = 0; mf < 4; mf++)
#pragma unroll
      for (int nf = 0; nf < 4; nf++)
        acc[mf][nf] = __builtin_amdgcn_mfma_f32_16x16x32_f16(af[mf], bf[nf], acc[mf][nf], 0, 0, 0);
  }

#pragma unroll
  for (int mf = 0; mf < 4; mf++)
#pragma unroll
    for (int reg = 0; reg < 4; reg++) {
      const int row = m0 + wm * 64 + mf * 16 + lq * 4 + reg;
#pragma unroll
      for (int nf = 0; nf < 4; nf++) {
        const int col = n0 + wn * 64 + nf * 16 + lr;
        float v = acc[mf][nf][reg];
        if (bias) v += bias[col];
        if (OUT_BF16) ((unsigned short*)Cv)[(size_t)row * N + col] = f2bf(v);
        else          ((float*)Cv)[(size_t)row * N + col] = v;
      }
    }
}

// -------- fused conv1+IN1+relu+conv2+IN2+sigmoid, f16 MFMA, 2 blocks/CU --------
// grid 1024 (one image), 512 thr = 8 waves. LDS 80,256 B:
//   yB half[4][1156][8] @0 (73,984) | wH2 @73,984 (5,760) | statA f32[64] @79,744
//   aL f32[32] @80,000 | cL f32[32] @80,128
// Overlays on yB: wH1 (23,040 B, pre-conv1) and transF f32[8][1032] (post-conv2).
// conv1 A-operands come straight from global rpe (f32->f16 cvt in reg): each
// tap-read = 16 consecutive pixels x 128 B = 2 KB coalesced; 9 taps of a tile
// revisit a ~7 KB window -> L1-resident after first touch.
__global__ __launch_bounds__(512, 4) void conv_fused2(
    const float* __restrict__ rpe,
    const float* __restrict__ c1w, const float* __restrict__ g1, const float* __restrict__ b1,
    const float* __restrict__ c2w, const float* __restrict__ g2, const float* __restrict__ b2,
    float* __restrict__ wout)
{
  extern __shared__ __align__(16) char smem[];
  unsigned short* yB  = (unsigned short*)smem;            // 36,992 halves
  unsigned short* wH1 = yB;                               // overlay: [tap*32+ct*16+r][40]
  unsigned short* wH2 = (unsigned short*)(smem + 73984);  // [tap*8+oc][40]
  float* statA = (float*)(smem + 79744);                  // 64
  float* aL    = (float*)(smem + 80000);                  // 32
  float* cL    = (float*)(smem + 80128);                  // 32
  float* transF = (float*)smem;                           // overlay [8][1032] post-conv2

  const int tid = threadIdx.x;
  const int wv = tid >> 6, ln = tid & 63;
  const int lr = ln & 15, lq = ln >> 4;
  const int p = blockIdx.x;

  if (tid < 64) statA[tid] = 0.f;

  // ---- stage weights coalesced -> LDS f16, stride-40 rows in consumer order
  for (int t = tid; t < 9216; t += 512) {
    int oc = t / 288, rem = t - oc * 288;
    int ic = rem / 9, tap = rem - ic * 9;
    wH1[(tap * 32 + (oc & 1) * 16 + (oc >> 1)) * 40 + ic] = __half_as_ushort(__float2half(c1w[t]));
  }
  for (int t = tid; t < 2304; t += 512) {
    int oc = t / 288, rem = t - oc * 288;
    int ic = rem / 9, tap = rem - ic * 9;
    wH2[(tap * 8 + oc) * 40 + ic] = __half_as_ushort(__float2half(c2w[t]));
  }
  __syncthreads();

  // ---- w1 fragments (lane lr: oc = 2*lr + ct), conflict-free stride-40 reads
  f16x8 w1f[2][9];
  const int ic0 = lq * 8;
#pragma unroll
  for (int ct = 0; ct < 2; ct++)
#pragma unroll
    for (int tap = 0; tap < 9; tap++)
      w1f[ct][tap] = *(const f16x8*)&wH1[(tap * 32 + ct * 16 + lr) * 40 + ic0];
  __syncthreads();  // wH1 fully consumed before conv1 writes yB

  // ---- conv1: A from GLOBAL, 73 row-tiles of 16 out-pixels
  const float* src = rpe + (size_t)(((p >> 5) + 2) * 36 + (p & 31) + 2) * 41472;
  constexpr int TOFF[9] = {0, 32, 64, 1152, 1184, 1216, 2304, 2336, 2368}; // (tr*36+tc)*32 floats
  float s0 = 0.f, q0 = 0.f, s1 = 0.f, q1 = 0.f;
  for (int t = wv; t < 73; t += 8) {
    int m = t * 16 + lr;
    int ms = m < 1155 ? m : 1155;
    const float* ab = src + ((ms / 34) * 36 + (ms % 34)) * 32 + lq * 8;
    f32x4 c0 = {0.f, 0.f, 0.f, 0.f}, c1v = {0.f, 0.f, 0.f, 0.f};
#pragma unroll
    for (int tap = 0; tap < 9; tap++) {
      float4 a0 = *(const float4*)(ab + TOFF[tap]);
      float4 a1 = *(const float4*)(ab + TOFF[tap] + 4);
      f16x8 av;
      av[0]=(_Float16)a0.x; av[1]=(_Float16)a0.y; av[2]=(_Float16)a0.z; av[3]=(_Float16)a0.w;
      av[4]=(_Float16)a1.x; av[5]=(_Float16)a1.y; av[6]=(_Float16)a1.z; av[7]=(_Float16)a1.w;
      c0  = __builtin_amdgcn_mfma_f32_16x16x32_f16(av, w1f[0][tap], c0, 0, 0, 0);
      c1v = __builtin_amdgcn_mfma_f32_16x16x32_f16(av, w1f[1][tap], c1v, 0, 0, 0);
    }
#pragma unroll
    for (int r = 0; r < 4; r++) {
      int mo = t * 16 + lq * 4 + r;
      if (mo < 1156) {
        float v0 = c0[r], v1 = c1v[r];   // channels 2*lr, 2*lr+1
        unsigned u = (unsigned)__half_as_ushort(__float2half(v0))
                   | ((unsigned)__half_as_ushort(__float2half(v1)) << 16);
        *(unsigned*)&yB[(lr >> 2) * 9248 + mo * 8 + ((lr * 2) & 7)] = u;
        s0 += v0; q0 += v0 * v0; s1 += v1; q1 += v1 * v1;
      }
    }
  }
#pragma unroll
  for (int off = 16; off < 64; off <<= 1) {
    s0 += __shfl_xor(s0, off); q0 += __shfl_xor(q0, off);
    s1 += __shfl_xor(s1, off); q1 += __shfl_xor(q1, off);
  }
  if (ln < 16) {
    atomicAdd(&statA[ln], s0);      atomicAdd(&statA[16 + ln], q0);
    atomicAdd(&statA[32 + ln], s1); atomicAdd(&statA[48 + ln], q1);
  }
  __syncthreads();
  if (tid < 32) {
    int cti = tid >> 4, lri = tid & 15;   // ch = 2*lri + cti
    float s = statA[cti * 32 + lri];
    float q = statA[cti * 32 + 16 + lri];
    int ch = 2 * lri + cti;
    float mu = s * (1.f / 1156.f);
    float var = q * (1.f / 1156.f) - mu * mu;
    float a_ = rsqrtf(var + 1e-5f) * g1[ch];
    aL[ch] = a_; cL[ch] = b1[ch] - mu * a_;
  }
  if (tid < 16) statA[tid] = 0.f;  // IN2 slots (same-thread program order safe)
  __syncthreads();

  // ---- normalize + relu RMW on yB (group g holds channels 8g..8g+7, natural order)
  {
    int g = tid >> 7, base = tid & 127;
    unsigned short* yg = yB + g * 9248;
    for (int k = 0; k < 10; k++) {
      int pix = base + 128 * k;
      if (pix < 1156) {
        f16x8 raw = *(const f16x8*)&yg[pix * 8];
        f16x8 outv;
#pragma unroll
        for (int e = 0; e < 8; e++) {
          float v = (float)raw[e];
          outv[e] = (_Float16)fmaxf(v * aL[g * 8 + e] + cL[g * 8 + e], 0.f);
        }
        *(f16x8*)&yg[pix * 8] = outv;
      }
    }
  }
  __syncthreads();

  // ---- conv2: 8 tiles/wave, z in regs
  f16x8 w2f[9];
#pragma unroll
  for (int tap = 0; tap < 9; tap++)
    w2f[tap] = *(const f16x8*)&wH2[(tap * 8 + (lr & 7)) * 40 + ic0];

  constexpr int OFF2[9] = {0, 8, 16, 272, 280, 288, 544, 552, 560};
  const unsigned short* yBg = yB + lq * 9248;
  f32x4 zsave[8];
  float s2 = 0.f, q2 = 0.f;
#pragma unroll
  for (int i = 0; i < 8; i++) {
    int t = wv + i * 8;
    int m = t * 16 + lr;
    const unsigned short* ab = yBg + ((m >> 5) * 34 + (m & 31)) * 8;
    f32x4 cc = {0.f, 0.f, 0.f, 0.f};
#pragma unroll
    for (int tap = 0; tap < 9; tap++) {
      f16x8 av = *(const f16x8*)(ab + OFF2[tap]);
      cc = __builtin_amdgcn_mfma_f32_16x16x32_f16(av, w2f[tap], cc, 0, 0, 0);
    }
    zsave[i] = cc;
#pragma unroll
    for (int r = 0; r < 4; r++) { s2 += cc[r]; q2 += cc[r] * cc[r]; }
  }
#pragma unroll
  for (int off = 16; off < 64; off <<= 1) {
    s2 += __shfl_xor(s2, off); q2 += __shfl_xor(q2, off);
  }
  if (ln < 8) { atomicAdd(&statA[ln], s2); atomicAdd(&statA[8 + ln], q2); }
  __syncthreads();   // conv2 reads of yB complete -> transF overlay safe

  if (lr < 8) {
#pragma unroll
    for (int i = 0; i < 8; i++) {
      int t = wv + i * 8;
#pragma unroll
      for (int r = 0; r < 4; r++)
        transF[lr * 1032 + t * 16 + lq * 4 + r] = zsave[i][r];
    }
  }
  if (tid < 8) {
    float s = statA[tid], q = statA[8 + tid];
    float mu = s * (1.f / 1024.f);
    float var = q * (1.f / 1024.f) - mu * mu;
    float a_ = rsqrtf(var + 1e-5f) * g2[tid];
    aL[tid] = a_; cL[tid] = b2[tid] - mu * a_;
  }
  __syncthreads();

  // ---- sigmoid + coalesced store: wout[oc][p][pix]
  for (int idx = tid; idx < 2048; idx += 512) {
    int oc = idx >> 8, p4 = (idx & 255) << 2;
    float4 v = *(const float4*)&transF[oc * 1032 + p4];
    float a_ = aL[oc], c_ = cL[oc];
    float4 o;
    o.x = 1.f / (1.f + __expf(-(v.x * a_ + c_)));
    o.y = 1.f / (1.f + __expf(-(v.y * a_ + c_)));
    o.z = 1.f / (1.f + __expf(-(v.z * a_ + c_)));
    o.w = 1.f / (1.f + __expf(-(v.w * a_ + c_)));
    *(float4*)(wout + ((size_t)oc << 20) + ((size_t)p << 10) + p4) = o;
  }
}

// ---------------- fused attention, bf16 MFMA 16x16x32 -------------------------
__global__ __launch_bounds__(256) void attn_kernel(
    const unsigned short* __restrict__ qkv,  // bf16 bits [8192][1536]
    const float* __restrict__ wppe,          // [8][1024][1024]
    float* __restrict__ oh)                  // [8192][512] = (b,n,h,d)
{
  __shared__ __align__(16) unsigned short k_lds[64 * 72];
  __shared__ __align__(16) unsigned short v_lds[64 * 72]; // transposed [d][m ^ swz]
  __shared__ __align__(16) unsigned short p_lds[4 * 16 * 72];
  const int tid = threadIdx.x;
  const int wv = tid >> 6, ln = tid & 63;
  const int lr = ln & 15, lq = ln >> 4;
  const int b = blockIdx.y >> 3, h = blockIdx.y & 7;
  const int n0 = blockIdx.x << 6;

  const size_t qoff = (size_t)((b << 10) + n0 + (wv << 4) + lr) * 1536 + (h << 6);
  bf16x8 qf0 = *(const bf16x8*)(qkv + qoff + lq * 8);
  bf16x8 qf1 = *(const bf16x8*)(qkv + qoff + 32 + lq * 8);

  f32x4 acc[4];
#pragma unroll
  for (int dt = 0; dt < 4; dt++) acc[dt] = (f32x4){0.f, 0.f, 0.f, 0.f};
  float den[4] = {0.f, 0.f, 0.f, 0.f};
  const float* wp = wppe + ((size_t)h << 20);

  for (int m0 = 0; m0 < 1024; m0 += 64) {
    __syncthreads();
    for (int t = tid; t < 512; t += 256) {
      int m = t >> 3, dq = t & 7;
      const unsigned short* kr = qkv + (size_t)((b << 10) + m0 + m) * 1536 + 512 + (h << 6) + dq * 8;
      *(uint4*)&k_lds[m * 72 + dq * 8] = *(const uint4*)kr;
      uint4 vvv = *(const uint4*)(kr + 512);
      unsigned short tmp[8];
      *(uint4*)tmp = vvv;
#pragma unroll
      for (int i = 0; i < 8; i++) {
        int d = dq * 8 + i;
        v_lds[d * 72 + (m ^ (((d >> 3) & 7) << 3))] = tmp[i];
      }
    }
    __syncthreads();

    f32x4 s[4];
#pragma unroll
    for (int mt = 0; mt < 4; mt++) {
      const unsigned short* kb = &k_lds[(mt * 16 + lr) * 72 + lq * 8];
      f32x4 cz = (f32x4){0.f, 0.f, 0.f, 0.f};
      cz = __builtin_amdgcn_mfma_f32_16x16x32_bf16(qf0, *(const bf16x8*)kb, cz, 0, 0, 0);
      cz = __builtin_amdgcn_mfma_f32_16x16x32_bf16(qf1, *(const bf16x8*)(kb + 32), cz, 0, 0, 0);
      s[mt] = cz;
    }
#pragma unroll
    for (int mt = 0; mt < 4; mt++)
#pragma unroll
      for (int reg = 0; reg < 4; reg++) {
        int rrow = lq * 4 + reg;
        float wvl = wp[(size_t)(n0 + (wv << 4) + rrow) * 1024 + (m0 + mt * 16 + lr)];
        float pv = wvl * __expf(s[mt][reg] * 0.125f);
        den[reg] += pv;
        p_lds[((wv << 4) + rrow) * 72 + mt * 16 + lr] = f2bf(pv);
      }
    const unsigned short* pb = &p_lds[((wv << 4) + lr) * 72];
    bf16x8 pa0 = *(const bf16x8*)(pb + lq * 8);
    bf16x8 pa1 = *(const bf16x8*)(pb + 32 + lq * 8);
#pragma unroll
    for (int dt = 0; dt < 4; dt++) {
      int d = dt * 16 + lr;
      int sw = ((d >> 3) & 7) << 3;
      const unsigned short* vb = &v_lds[d * 72];
      acc[dt] = __builtin_amdgcn_mfma_f32_16x16x32_bf16(pa0, *(const bf16x8*)(vb + ((lq * 8) ^ sw)), acc[dt], 0, 0, 0);
      acc[dt] = __builtin_amdgcn_mfma_f32_16x16x32_bf16(pa1, *(const bf16x8*)(vb + ((32 + lq * 8) ^ sw)), acc[dt], 0, 0, 0);
    }
  }
#pragma unroll
  for (int off = 1; off < 16; off <<= 1)
#pragma unroll
    for (int reg = 0; reg < 4; reg++) den[reg] += __shfl_xor(den[reg], off);
#pragma unroll
  for (int dt = 0; dt < 4; dt++)
#pragma unroll
    for (int reg = 0; reg < 4; reg++) {
      size_t row = (size_t)((b << 10) + n0 + (wv << 4) + lq * 4 + reg);
      oh[row * 512 + (h << 6) + dt * 16 + lr] = acc[dt][reg] / den[reg];
    }
}

// ---------------------------------------------------------------------------
extern "C" void kernel_launch(void* const* d_in, const int* in_sizes, int n_in,
                              void* d_out, int out_size, void* d_ws, size_t ws_size,
                              hipStream_t stream) {
  (void)in_sizes; (void)n_in; (void)out_size; (void)ws_size;
  const float* x     = (const float*)d_in[0];
  const float* rpe   = (const float*)d_in[1];
  const float* wqkv  = (const float*)d_in[2];
  const float* wproj = (const float*)d_in[3];
  const float* bproj = (const float*)d_in[4];
  const float* c1w   = (const float*)d_in[5];
  // d_in[6] = c1b: cancels exactly in the following instance-norm
  const float* g1w   = (const float*)d_in[7];
  const float* g1b   = (const float*)d_in[8];
  const float* c2w   = (const float*)d_in[9];
  // d_in[10] = c2b: cancels likewise
  const float* g2w   = (const float*)d_in[11];
  const float* g2b   = (const float*)d_in[12];
  float* out = (float*)d_out;

  char* ws = (char*)d_ws;
  unsigned short* qkv_bf = (unsigned short*)ws;            // 25,165,824 B
  float* wppe = (float*)(ws + 25165824);                   // 33,554,432 B
  float* ohb  = (float*)(ws + 58720256);                   // 16,777,216 B

  // 1) qkv = x @ wqkv^T  -> bf16 (f16 MFMA)
  gemm_f16_bt<true><<<dim3(12, 64), 256, 0, stream>>>(x, wqkv, qkv_bf, nullptr, 8192, 1536, 512);

  // 2) fused conv1+IN+relu+conv2+IN+sigmoid -> w (2 blocks/CU)
  const int ldsC = 80256;
  hipFuncSetAttribute(reinterpret_cast<const void*>(&conv_fused2),
                      hipFuncAttributeMaxDynamicSharedMemorySize, ldsC);
  conv_fused2<<<1024, 512, ldsC, stream>>>(rpe, c1w, g1w, g1b, c2w, g2w, g2b, wppe);

  // 3) fused attention
  attn_kernel<<<dim3(16, 64), 256, 0, stream>>>(qkv_bf, wppe, ohb);

  // 4) out = oh @ wproj^T + bproj (f16 MFMA)
  gemm_f16_bt<false><<<dim3(4, 64), 256, 0, stream>>>(ohb, wproj, out, bproj, 8192, 512, 512);
}

// Round 10
// 229.248 us; speedup vs baseline: 1.3207x; 1.3207x over previous
//
#include <hip/hip_runtime.h>
#include <hip/hip_fp16.h>

// MPA_16698832847132 — round 10: split conv with pre-baked weight fragments.
//  wprep: bakes w1/w2 MFMA fragments into ws in per-lane consumer order
//         (wave fragment load = one contiguous 1KB global read, L1-resident).
//  conv1_k2: r7 band kernel minus weight staging; writes y1g + per-block IN1
//            partial stats (non-atomic, disjoint).
//  conv2_k2: aL/cL from partials (512B); normalize+relu FUSED into y1 staging;
//            conv2+IN2+sigmoid as before.
// Workspace: qkv bf16 @0 | w f32 @25,165,824 | y1g f16 @58,720,256 (75,759,616;
//   ohb f32 overlays) | w1frag @134,479,872 | w2frag @134,498,304 | partialS @134,507,520

typedef __attribute__((ext_vector_type(8))) short bf16x8;
typedef __attribute__((ext_vector_type(8))) _Float16 f16x8;
typedef __attribute__((ext_vector_type(4))) float f32x4;

__device__ __forceinline__ unsigned short f2bf(float f) {
  unsigned u = __builtin_bit_cast(unsigned, f);
  u += 0x7FFFu + ((u >> 16) & 1u);
  return (unsigned short)(u >> 16);
}

// ---------------- weight fragment prep (once per launch) -----------------------
// w1frag[((tap*2+ct)*64+ln)*8+j] = f16(c1w[oc=2*(ln&15)+ct][ic=(ln>>4)*8+j][tap])
// w2frag[(tap*64+ln)*8+j]        = f16(c2w[oc=(ln&15)&7][ic=(ln>>4)*8+j][tap])
__global__ __launch_bounds__(256) void wprep(
    const float* __restrict__ c1w, const float* __restrict__ c2w,
    unsigned short* __restrict__ w1frag, unsigned short* __restrict__ w2frag)
{
  int t = blockIdx.x * 256 + threadIdx.x;
  if (t < 9216) {
    int j = t & 7, ln = (t >> 3) & 63, ctap = t >> 9;
    int tap = ctap >> 1, ct = ctap & 1;
    int oc = 2 * (ln & 15) + ct, ic = (ln >> 4) * 8 + j;
    w1frag[t] = __half_as_ushort(__float2half(c1w[(oc * 32 + ic) * 9 + tap]));
  }
  if (t < 4608) {
    int j = t & 7, ln = (t >> 3) & 63, tap = t >> 9;
    int oc = (ln & 15) & 7, ic = (ln >> 4) * 8 + j;
    w2frag[t] = __half_as_ushort(__float2half(c2w[(oc * 32 + ic) * 9 + tap]));
  }
}

// ---------------- C[M][N] = A[M][K] * B[N][K]^T (+bias), f16 MFMA --------------
template<bool OUT_BF16>
__global__ __launch_bounds__(256) void gemm_f16_bt(
    const float* __restrict__ A, const float* __restrict__ B,
    void* __restrict__ Cv, const float* __restrict__ bias,
    int M, int N, int K)
{
  __shared__ __align__(16) _Float16 As[128 * 40];
  __shared__ __align__(16) _Float16 Bs[128 * 40];
  const int tid = threadIdx.x;
  const int wv = tid >> 6, ln = tid & 63, lr = ln & 15, lq = ln >> 4;
  const int wm = wv >> 1, wn = wv & 1;
  const int m0 = blockIdx.y * 128, n0 = blockIdx.x * 128;

  f32x4 acc[4][4];
#pragma unroll
  for (int i = 0; i < 4; i++)
#pragma unroll
    for (int j = 0; j < 4; j++) acc[i][j] = (f32x4){0.f, 0.f, 0.f, 0.f};

  const int sr = tid >> 1, sk = (tid & 1) * 16;
  const float* Ap = A + (size_t)(m0 + sr) * K + sk;
  const float* Bp = B + (size_t)(n0 + sr) * K + sk;

  for (int k0 = 0; k0 < K; k0 += 32) {
    float4 av0 = *(const float4*)(Ap + k0);
    float4 av1 = *(const float4*)(Ap + k0 + 4);
    float4 av2 = *(const float4*)(Ap + k0 + 8);
    float4 av3 = *(const float4*)(Ap + k0 + 12);
    float4 bv0 = *(const float4*)(Bp + k0);
    float4 bv1 = *(const float4*)(Bp + k0 + 4);
    float4 bv2 = *(const float4*)(Bp + k0 + 8);
    float4 bv3 = *(const float4*)(Bp + k0 + 12);
    __syncthreads();
    {
      f16x8 p0, p1, r0, r1;
      p0[0]=(_Float16)av0.x; p0[1]=(_Float16)av0.y; p0[2]=(_Float16)av0.z; p0[3]=(_Float16)av0.w;
      p0[4]=(_Float16)av1.x; p0[5]=(_Float16)av1.y; p0[6]=(_Float16)av1.z; p0[7]=(_Float16)av1.w;
      p1[0]=(_Float16)av2.x; p1[1]=(_Float16)av2.y; p1[2]=(_Float16)av2.z; p1[3]=(_Float16)av2.w;
      p1[4]=(_Float16)av3.x; p1[5]=(_Float16)av3.y; p1[6]=(_Float16)av3.z; p1[7]=(_Float16)av3.w;
      r0[0]=(_Float16)bv0.x; r0[1]=(_Float16)bv0.y; r0[2]=(_Float16)bv0.z; r0[3]=(_Float16)bv0.w;
      r0[4]=(_Float16)bv1.x; r0[5]=(_Float16)bv1.y; r0[6]=(_Float16)bv1.z; r0[7]=(_Float16)bv1.w;
      r1[0]=(_Float16)bv2.x; r1[1]=(_Float16)bv2.y; r1[2]=(_Float16)bv2.z; r1[3]=(_Float16)bv2.w;
      r1[4]=(_Float16)bv3.x; r1[5]=(_Float16)bv3.y; r1[6]=(_Float16)bv3.z; r1[7]=(_Float16)bv3.w;
      *(f16x8*)&As[sr * 40 + sk] = p0;
      *(f16x8*)&As[sr * 40 + sk + 8] = p1;
      *(f16x8*)&Bs[sr * 40 + sk] = r0;
      *(f16x8*)&Bs[sr * 40 + sk + 8] = r1;
    }
    __syncthreads();
    f16x8 af[4], bf[4];
#pragma unroll
    for (int mf = 0; mf < 4; mf++)
      af[mf] = *(const f16x8*)&As[(wm * 64 + mf * 16 + lr) * 40 + lq * 8];
#pragma unroll
    for (int nf = 0; nf < 4; nf++)
      bf[nf] = *(const f16x8*)&Bs[(wn * 64 + nf * 16 + lr) * 40 + lq * 8];
#pragma unroll
    for (int mf = 0; mf < 4; mf++)
#pragma unroll
      for (int nf = 0; nf < 4; nf++)
        acc[mf][nf] = __builtin_amdgcn_mfma_f32_16x16x32_f16(af[mf], bf[nf], acc[mf][nf], 0, 0, 0);
  }

#pragma unroll
  for (int mf = 0; mf < 4; mf++)
#pragma unroll
    for (int reg = 0; reg < 4; reg++) {
      const int row = m0 + wm * 64 + mf * 16 + lq * 4 + reg;
#pragma unroll
      for (int nf = 0; nf < 4; nf++) {
        const int col = n0 + wn * 64 + nf * 16 + lr;
        float v = acc[mf][nf][reg];
        if (bias) v += bias[col];
        if (OUT_BF16) ((unsigned short*)Cv)[(size_t)row * N + col] = f2bf(v);
        else          ((float*)Cv)[(size_t)row * N + col] = v;
      }
    }
}

// ---------------- conv1 (3x3, 32->32ch) -> y1 global + IN1 partials ------------
// grid 2048 = (img<<1)|half; 512 thr; LDS 44,032 B (input band + statA).
__global__ __launch_bounds__(512, 4) void conv1_k2(
    const float* __restrict__ rpe, const unsigned short* __restrict__ w1frag,
    unsigned short* __restrict__ y1g, float* __restrict__ partialS)
{
  extern __shared__ __align__(16) char smem[];
  unsigned short* inH = (unsigned short*)smem;            // 4 x 5472 halves
  float* statA = (float*)(smem + 43776);                  // 64

  const int tid = threadIdx.x;
  const int wv = tid >> 6, ln = tid & 63;
  const int lr = ln & 15, lq = ln >> 4;
  const int img = blockIdx.x >> 1, h = blockIdx.x & 1;

  if (tid < 64) statA[tid] = 0.f;

  // stage input band (19 rows = 684 px, channel-major groups)
  const float* src = rpe + (size_t)(((img >> 5) + 2) * 36 + (img & 31) + 2) * 41472
                   + h * 19584;
  for (int t = tid; t < 5472; t += 512) {
    int pix = t >> 3, dq = (t & 7) << 2;
    float4 v = *(const float4*)(src + t * 4);
    __half2 h0 = __floats2half2_rn(v.x, v.y);
    __half2 h1 = __floats2half2_rn(v.z, v.w);
    uint2 u; u.x = __builtin_bit_cast(unsigned, h0); u.y = __builtin_bit_cast(unsigned, h1);
    *(uint2*)&inH[(dq >> 3) * 5472 + pix * 8 + (dq & 7)] = u;
  }
  // fragments: one contiguous 1KB wave-load per (ct,tap); L1-resident after blk 0
  f16x8 w1f[2][9];
#pragma unroll
  for (int ct = 0; ct < 2; ct++)
#pragma unroll
    for (int tap = 0; tap < 9; tap++)
      w1f[ct][tap] = *(const f16x8*)&w1frag[((tap * 2 + ct) * 64 + ln) * 8];
  __syncthreads();

  constexpr int OFF1[9] = {0, 8, 16, 288, 296, 304, 576, 584, 592};
  unsigned short* ybase = y1g + (size_t)img * 36992 + (lr >> 2) * 9248 + ((2 * lr) & 7);
  const unsigned short* inAg = inH + lq * 5472;
  float s0 = 0.f, q0 = 0.f, s1 = 0.f, q1 = 0.f;
  for (int t = wv; t < 37; t += 8) {
    int m = t * 16 + lr;
    int ms = m < 577 ? m : 577;
    const unsigned short* ab = inAg + ((ms / 34) * 36 + (ms % 34)) * 8;
    f32x4 c0 = {0.f, 0.f, 0.f, 0.f}, c1v = {0.f, 0.f, 0.f, 0.f};
#pragma unroll
    for (int tap = 0; tap < 9; tap++) {
      f16x8 av = *(const f16x8*)(ab + OFF1[tap]);
      c0  = __builtin_amdgcn_mfma_f32_16x16x32_f16(av, w1f[0][tap], c0, 0, 0, 0);
      c1v = __builtin_amdgcn_mfma_f32_16x16x32_f16(av, w1f[1][tap], c1v, 0, 0, 0);
    }
#pragma unroll
    for (int r = 0; r < 4; r++) {
      int mo = t * 16 + lq * 4 + r;
      if (mo < 578) {
        float v0 = c0[r], v1 = c1v[r];   // channels 2*lr, 2*lr+1
        unsigned u = (unsigned)__half_as_ushort(__float2half(v0))
                   | ((unsigned)__half_as_ushort(__float2half(v1)) << 16);
        *(unsigned*)(ybase + (h * 578 + mo) * 8) = u;
        s0 += v0; q0 += v0 * v0; s1 += v1; q1 += v1 * v1;
      }
    }
  }
  // reduce within wave (lanes sharing lr), combine across waves, write partials
#pragma unroll
  for (int off = 16; off < 64; off <<= 1) {
    s0 += __shfl_xor(s0, off); q0 += __shfl_xor(q0, off);
    s1 += __shfl_xor(s1, off); q1 += __shfl_xor(q1, off);
  }
  if (ln < 16) {
    atomicAdd(&statA[ln], s0);      atomicAdd(&statA[16 + ln], q0);
    atomicAdd(&statA[32 + ln], s1); atomicAdd(&statA[48 + ln], q1);
  }
  __syncthreads();
  if (tid < 64) partialS[(size_t)img * 128 + h * 64 + tid] = statA[tid];
}

// ------- conv2_k2: aL/cL from partials; normalize fused into staging ----------
// grid 1024 (one image); 512 thr; LDS 74,304 B.
__global__ __launch_bounds__(512, 4) void conv2_k2(
    const unsigned short* __restrict__ y1g, const unsigned short* __restrict__ w2frag,
    const float* __restrict__ partialS,
    const float* __restrict__ g1, const float* __restrict__ b1,
    const float* __restrict__ g2, const float* __restrict__ b2,
    float* __restrict__ wout)
{
  extern __shared__ __align__(16) char smem[];
  unsigned short* yB = (unsigned short*)smem;             // [g][1156][8] halves
  float* statA = (float*)(smem + 73984);                  // 16 (IN2)
  float* aL    = statA + 16;                              // 32
  float* cL    = aL + 32;                                 // 32
  float* transF = (float*)smem;                           // overlay [8][1032]

  const int tid = threadIdx.x;
  const int wv = tid >> 6, ln = tid & 63;
  const int lr = ln & 15, lq = ln >> 4;
  const int p = blockIdx.x;

  if (tid < 16) statA[tid] = 0.f;
  if (tid < 32) {
    int cti = tid >> 4, lri = tid & 15;           // ch = 2*lri + cti
    const float* P = partialS + (size_t)p * 128;
    float s = P[cti * 32 + lri]      + P[64 + cti * 32 + lri];
    float q = P[cti * 32 + 16 + lri] + P[64 + cti * 32 + 16 + lri];
    int ch = 2 * lri + cti;
    float mu = s * (1.f / 1156.f);
    float var = q * (1.f / 1156.f) - mu * mu;
    float a_ = rsqrtf(var + 1e-5f) * g1[ch];
    aL[ch] = a_; cL[ch] = b1[ch] - mu * a_;
  }
  __syncthreads();

  // stage y1 with FUSED normalize + relu (one touch per element)
  const unsigned short* srcY = y1g + (size_t)p * 36992;
#pragma unroll
  for (int g = 0; g < 4; g++) {
    for (int pix = tid; pix < 1156; pix += 512) {
      f16x8 raw = *(const f16x8*)&srcY[g * 9248 + pix * 8];
      f16x8 outv;
#pragma unroll
      for (int e = 0; e < 8; e++) {
        float v = (float)raw[e];
        outv[e] = (_Float16)fmaxf(v * aL[g * 8 + e] + cL[g * 8 + e], 0.f);
      }
      *(f16x8*)&yB[g * 9248 + pix * 8] = outv;
    }
  }
  __syncthreads();

  // conv2: fragments from global (1KB wave-loads), 8 tiles/wave, z in regs
  f16x8 w2f[9];
#pragma unroll
  for (int tap = 0; tap < 9; tap++)
    w2f[tap] = *(const f16x8*)&w2frag[(tap * 64 + ln) * 8];

  constexpr int OFF2[9] = {0, 8, 16, 272, 280, 288, 544, 552, 560};
  const unsigned short* yBg = yB + lq * 9248;
  f32x4 zsave[8];
  float s2 = 0.f, q2 = 0.f;
#pragma unroll
  for (int i = 0; i < 8; i++) {
    int t = wv + i * 8;
    int m = t * 16 + lr;
    const unsigned short* ab = yBg + ((m >> 5) * 34 + (m & 31)) * 8;
    f32x4 cc = {0.f, 0.f, 0.f, 0.f};
#pragma unroll
    for (int tap = 0; tap < 9; tap++) {
      f16x8 av = *(const f16x8*)(ab + OFF2[tap]);
      cc = __builtin_amdgcn_mfma_f32_16x16x32_f16(av, w2f[tap], cc, 0, 0, 0);
    }
    zsave[i] = cc;
#pragma unroll
    for (int r = 0; r < 4; r++) { s2 += cc[r]; q2 += cc[r] * cc[r]; }
  }
#pragma unroll
  for (int off = 16; off < 64; off <<= 1) {
    s2 += __shfl_xor(s2, off); q2 += __shfl_xor(q2, off);
  }
  if (ln < 8) { atomicAdd(&statA[ln], s2); atomicAdd(&statA[8 + ln], q2); }
  __syncthreads();   // conv2 reads of yB complete -> transF overlay safe

  if (lr < 8) {
#pragma unroll
    for (int i = 0; i < 8; i++) {
      int t = wv + i * 8;
#pragma unroll
      for (int r = 0; r < 4; r++)
        transF[lr * 1032 + t * 16 + lq * 4 + r] = zsave[i][r];
    }
  }
  if (tid < 8) {
    float s = statA[tid], q = statA[8 + tid];
    float mu = s * (1.f / 1024.f);
    float var = q * (1.f / 1024.f) - mu * mu;
    float a_ = rsqrtf(var + 1e-5f) * g2[tid];
    aL[tid] = a_; cL[tid] = b2[tid] - mu * a_;
  }
  __syncthreads();

  for (int idx = tid; idx < 2048; idx += 512) {
    int oc = idx >> 8, p4 = (idx & 255) << 2;
    float4 v = *(const float4*)&transF[oc * 1032 + p4];
    float a_ = aL[oc], c_ = cL[oc];
    float4 o;
    o.x = 1.f / (1.f + __expf(-(v.x * a_ + c_)));
    o.y = 1.f / (1.f + __expf(-(v.y * a_ + c_)));
    o.z = 1.f / (1.f + __expf(-(v.z * a_ + c_)));
    o.w = 1.f / (1.f + __expf(-(v.w * a_ + c_)));
    *(float4*)(wout + ((size_t)oc << 20) + ((size_t)p << 10) + p4) = o;
  }
}

// ---------------- fused attention, bf16 MFMA 16x16x32 -------------------------
__global__ __launch_bounds__(256) void attn_kernel(
    const unsigned short* __restrict__ qkv,  // bf16 bits [8192][1536]
    const float* __restrict__ wppe,          // [8][1024][1024]
    float* __restrict__ oh)                  // [8192][512] = (b,n,h,d)
{
  __shared__ __align__(16) unsigned short k_lds[64 * 72];
  __shared__ __align__(16) unsigned short v_lds[64 * 72]; // transposed [d][m ^ swz]
  __shared__ __align__(16) unsigned short p_lds[4 * 16 * 72];
  const int tid = threadIdx.x;
  const int wv = tid >> 6, ln = tid & 63;
  const int lr = ln & 15, lq = ln >> 4;
  const int b = blockIdx.y >> 3, h = blockIdx.y & 7;
  const int n0 = blockIdx.x << 6;

  const size_t qoff = (size_t)((b << 10) + n0 + (wv << 4) + lr) * 1536 + (h << 6);
  bf16x8 qf0 = *(const bf16x8*)(qkv + qoff + lq * 8);
  bf16x8 qf1 = *(const bf16x8*)(qkv + qoff + 32 + lq * 8);

  f32x4 acc[4];
#pragma unroll
  for (int dt = 0; dt < 4; dt++) acc[dt] = (f32x4){0.f, 0.f, 0.f, 0.f};
  float den[4] = {0.f, 0.f, 0.f, 0.f};
  const float* wp = wppe + ((size_t)h << 20);

  for (int m0 = 0; m0 < 1024; m0 += 64) {
    __syncthreads();
    for (int t = tid; t < 512; t += 256) {
      int m = t >> 3, dq = t & 7;
      const unsigned short* kr = qkv + (size_t)((b << 10) + m0 + m) * 1536 + 512 + (h << 6) + dq * 8;
      *(uint4*)&k_lds[m * 72 + dq * 8] = *(const uint4*)kr;
      uint4 vvv = *(const uint4*)(kr + 512);
      unsigned short tmp[8];
      *(uint4*)tmp = vvv;
#pragma unroll
      for (int i = 0; i < 8; i++) {
        int d = dq * 8 + i;
        v_lds[d * 72 + (m ^ (((d >> 3) & 7) << 3))] = tmp[i];
      }
    }
    __syncthreads();

    f32x4 s[4];
#pragma unroll
    for (int mt = 0; mt < 4; mt++) {
      const unsigned short* kb = &k_lds[(mt * 16 + lr) * 72 + lq * 8];
      f32x4 cz = (f32x4){0.f, 0.f, 0.f, 0.f};
      cz = __builtin_amdgcn_mfma_f32_16x16x32_bf16(qf0, *(const bf16x8*)kb, cz, 0, 0, 0);
      cz = __builtin_amdgcn_mfma_f32_16x16x32_bf16(qf1, *(const bf16x8*)(kb + 32), cz, 0, 0, 0);
      s[mt] = cz;
    }
#pragma unroll
    for (int mt = 0; mt < 4; mt++)
#pragma unroll
      for (int reg = 0; reg < 4; reg++) {
        int rrow = lq * 4 + reg;
        float wvl = wp[(size_t)(n0 + (wv << 4) + rrow) * 1024 + (m0 + mt * 16 + lr)];
        float pv = wvl * __expf(s[mt][reg] * 0.125f);
        den[reg] += pv;
        p_lds[((wv << 4) + rrow) * 72 + mt * 16 + lr] = f2bf(pv);
      }
    const unsigned short* pb = &p_lds[((wv << 4) + lr) * 72];
    bf16x8 pa0 = *(const bf16x8*)(pb + lq * 8);
    bf16x8 pa1 = *(const bf16x8*)(pb + 32 + lq * 8);
#pragma unroll
    for (int dt = 0; dt < 4; dt++) {
      int d = dt * 16 + lr;
      int sw = ((d >> 3) & 7) << 3;
      const unsigned short* vb = &v_lds[d * 72];
      acc[dt] = __builtin_amdgcn_mfma_f32_16x16x32_bf16(pa0, *(const bf16x8*)(vb + ((lq * 8) ^ sw)), acc[dt], 0, 0, 0);
      acc[dt] = __builtin_amdgcn_mfma_f32_16x16x32_bf16(pa1, *(const bf16x8*)(vb + ((32 + lq * 8) ^ sw)), acc[dt], 0, 0, 0);
    }
  }
#pragma unroll
  for (int off = 1; off < 16; off <<= 1)
#pragma unroll
    for (int reg = 0; reg < 4; reg++) den[reg] += __shfl_xor(den[reg], off);
#pragma unroll
  for (int dt = 0; dt < 4; dt++)
#pragma unroll
    for (int reg = 0; reg < 4; reg++) {
      size_t row = (size_t)((b << 10) + n0 + (wv << 4) + lq * 4 + reg);
      oh[row * 512 + (h << 6) + dt * 16 + lr] = acc[dt][reg] / den[reg];
    }
}

// ---------------------------------------------------------------------------
extern "C" void kernel_launch(void* const* d_in, const int* in_sizes, int n_in,
                              void* d_out, int out_size, void* d_ws, size_t ws_size,
                              hipStream_t stream) {
  (void)in_sizes; (void)n_in; (void)out_size; (void)ws_size;
  const float* x     = (const float*)d_in[0];
  const float* rpe   = (const float*)d_in[1];
  const float* wqkv  = (const float*)d_in[2];
  const float* wproj = (const float*)d_in[3];
  const float* bproj = (const float*)d_in[4];
  const float* c1w   = (const float*)d_in[5];
  // d_in[6] = c1b: cancels exactly in the following instance-norm
  const float* g1w   = (const float*)d_in[7];
  const float* g1b   = (const float*)d_in[8];
  const float* c2w   = (const float*)d_in[9];
  // d_in[10] = c2b: cancels likewise
  const float* g2w   = (const float*)d_in[11];
  const float* g2b   = (const float*)d_in[12];
  float* out = (float*)d_out;

  char* ws = (char*)d_ws;
  unsigned short* qkv_bf = (unsigned short*)ws;             // 25,165,824 B
  float* wppe = (float*)(ws + 25165824);                    // 33,554,432 B
  unsigned short* y1g = (unsigned short*)(ws + 58720256);   // 75,759,616 B
  float* ohb = (float*)(ws + 58720256);                     // overlays y1g (dead after conv2_k2)
  unsigned short* w1frag = (unsigned short*)(ws + 134479872); // 18,432 B
  unsigned short* w2frag = (unsigned short*)(ws + 134498304); // 9,216 B
  float* partialS = (float*)(ws + 134507520);               // 524,288 B

  // 0) bake weight fragments
  wprep<<<36, 256, 0, stream>>>(c1w, c2w, w1frag, w2frag);

  // 1) qkv = x @ wqkv^T  -> bf16 (f16 MFMA)
  gemm_f16_bt<true><<<dim3(12, 64), 256, 0, stream>>>(x, wqkv, qkv_bf, nullptr, 8192, 1536, 512);

  // 2) conv1 -> y1g + IN1 partials
  const int lds1 = 44032;
  hipFuncSetAttribute(reinterpret_cast<const void*>(&conv1_k2),
                      hipFuncAttributeMaxDynamicSharedMemorySize, lds1);
  conv1_k2<<<2048, 512, lds1, stream>>>(rpe, w1frag, y1g, partialS);

  // 3) IN1+relu (fused in staging) + conv2 + IN2 + sigmoid -> w
  const int lds2 = 74304;
  hipFuncSetAttribute(reinterpret_cast<const void*>(&conv2_k2),
                      hipFuncAttributeMaxDynamicSharedMemorySize, lds2);
  conv2_k2<<<1024, 512, lds2, stream>>>(y1g, w2frag, partialS, g1w, g1b, g2w, g2b, wppe);

  // 4) fused attention
  attn_kernel<<<dim3(16, 64), 256, 0, stream>>>(qkv_bf, wppe, ohb);

  // 5) out = oh @ wproj^T + bproj (f16 MFMA)
  gemm_f16_bt<false><<<dim3(4, 64), 256, 0, stream>>>(ohb, wproj, out, bproj, 8192, 512, 512);
}

// Round 11
// 226.118 us; speedup vs baseline: 1.3390x; 1.0138x over previous
//
#include <hip/hip_runtime.h>
#include <hip/hip_fp16.h>

// MPA_16698832847132 — round 11: coalesced y1 layout [img][pix][32].
//  r10's split conv wrote y1 channel-group-major -> every wave-store was 16
//  scattered 16B slivers (4x write amplification). Now conv1 stores contiguous
//  64B segments; conv2's staging pass does the transpose to channel-major LDS
//  (coalesced reads) with the IN1 normalize+relu fused in.
// Workspace: qkv bf16 @0 | w f32 @25,165,824 | y1g f16 @58,720,256 (75,759,616;
//   ohb f32 overlays) | w1frag @134,479,872 | w2frag @134,498,304 | partialS @134,507,520

typedef __attribute__((ext_vector_type(8))) short bf16x8;
typedef __attribute__((ext_vector_type(8))) _Float16 f16x8;
typedef __attribute__((ext_vector_type(4))) float f32x4;

__device__ __forceinline__ unsigned short f2bf(float f) {
  unsigned u = __builtin_bit_cast(unsigned, f);
  u += 0x7FFFu + ((u >> 16) & 1u);
  return (unsigned short)(u >> 16);
}

// ---------------- weight fragment prep (once per launch) -----------------------
__global__ __launch_bounds__(256) void wprep(
    const float* __restrict__ c1w, const float* __restrict__ c2w,
    unsigned short* __restrict__ w1frag, unsigned short* __restrict__ w2frag)
{
  int t = blockIdx.x * 256 + threadIdx.x;
  if (t < 9216) {
    int j = t & 7, ln = (t >> 3) & 63, ctap = t >> 9;
    int tap = ctap >> 1, ct = ctap & 1;
    int oc = 2 * (ln & 15) + ct, ic = (ln >> 4) * 8 + j;
    w1frag[t] = __half_as_ushort(__float2half(c1w[(oc * 32 + ic) * 9 + tap]));
  }
  if (t < 4608) {
    int j = t & 7, ln = (t >> 3) & 63, tap = t >> 9;
    int oc = (ln & 15) & 7, ic = (ln >> 4) * 8 + j;
    w2frag[t] = __half_as_ushort(__float2half(c2w[(oc * 32 + ic) * 9 + tap]));
  }
}

// ---------------- C[M][N] = A[M][K] * B[N][K]^T (+bias), f16 MFMA --------------
template<bool OUT_BF16>
__global__ __launch_bounds__(256) void gemm_f16_bt(
    const float* __restrict__ A, const float* __restrict__ B,
    void* __restrict__ Cv, const float* __restrict__ bias,
    int M, int N, int K)
{
  __shared__ __align__(16) _Float16 As[128 * 40];
  __shared__ __align__(16) _Float16 Bs[128 * 40];
  const int tid = threadIdx.x;
  const int wv = tid >> 6, ln = tid & 63, lr = ln & 15, lq = ln >> 4;
  const int wm = wv >> 1, wn = wv & 1;
  const int m0 = blockIdx.y * 128, n0 = blockIdx.x * 128;

  f32x4 acc[4][4];
#pragma unroll
  for (int i = 0; i < 4; i++)
#pragma unroll
    for (int j = 0; j < 4; j++) acc[i][j] = (f32x4){0.f, 0.f, 0.f, 0.f};

  const int sr = tid >> 1, sk = (tid & 1) * 16;
  const float* Ap = A + (size_t)(m0 + sr) * K + sk;
  const float* Bp = B + (size_t)(n0 + sr) * K + sk;

  for (int k0 = 0; k0 < K; k0 += 32) {
    float4 av0 = *(const float4*)(Ap + k0);
    float4 av1 = *(const float4*)(Ap + k0 + 4);
    float4 av2 = *(const float4*)(Ap + k0 + 8);
    float4 av3 = *(const float4*)(Ap + k0 + 12);
    float4 bv0 = *(const float4*)(Bp + k0);
    float4 bv1 = *(const float4*)(Bp + k0 + 4);
    float4 bv2 = *(const float4*)(Bp + k0 + 8);
    float4 bv3 = *(const float4*)(Bp + k0 + 12);
    __syncthreads();
    {
      f16x8 p0, p1, r0, r1;
      p0[0]=(_Float16)av0.x; p0[1]=(_Float16)av0.y; p0[2]=(_Float16)av0.z; p0[3]=(_Float16)av0.w;
      p0[4]=(_Float16)av1.x; p0[5]=(_Float16)av1.y; p0[6]=(_Float16)av1.z; p0[7]=(_Float16)av1.w;
      p1[0]=(_Float16)av2.x; p1[1]=(_Float16)av2.y; p1[2]=(_Float16)av2.z; p1[3]=(_Float16)av2.w;
      p1[4]=(_Float16)av3.x; p1[5]=(_Float16)av3.y; p1[6]=(_Float16)av3.z; p1[7]=(_Float16)av3.w;
      r0[0]=(_Float16)bv0.x; r0[1]=(_Float16)bv0.y; r0[2]=(_Float16)bv0.z; r0[3]=(_Float16)bv0.w;
      r0[4]=(_Float16)bv1.x; r0[5]=(_Float16)bv1.y; r0[6]=(_Float16)bv1.z; r0[7]=(_Float16)bv1.w;
      r1[0]=(_Float16)bv2.x; r1[1]=(_Float16)bv2.y; r1[2]=(_Float16)bv2.z; r1[3]=(_Float16)bv2.w;
      r1[4]=(_Float16)bv3.x; r1[5]=(_Float16)bv3.y; r1[6]=(_Float16)bv3.z; r1[7]=(_Float16)bv3.w;
      *(f16x8*)&As[sr * 40 + sk] = p0;
      *(f16x8*)&As[sr * 40 + sk + 8] = p1;
      *(f16x8*)&Bs[sr * 40 + sk] = r0;
      *(f16x8*)&Bs[sr * 40 + sk + 8] = r1;
    }
    __syncthreads();
    f16x8 af[4], bf[4];
#pragma unroll
    for (int mf = 0; mf < 4; mf++)
      af[mf] = *(const f16x8*)&As[(wm * 64 + mf * 16 + lr) * 40 + lq * 8];
#pragma unroll
    for (int nf = 0; nf < 4; nf++)
      bf[nf] = *(const f16x8*)&Bs[(wn * 64 + nf * 16 + lr) * 40 + lq * 8];
#pragma unroll
    for (int mf = 0; mf < 4; mf++)
#pragma unroll
      for (int nf = 0; nf < 4; nf++)
        acc[mf][nf] = __builtin_amdgcn_mfma_f32_16x16x32_f16(af[mf], bf[nf], acc[mf][nf], 0, 0, 0);
  }

#pragma unroll
  for (int mf = 0; mf < 4; mf++)
#pragma unroll
    for (int reg = 0; reg < 4; reg++) {
      const int row = m0 + wm * 64 + mf * 16 + lq * 4 + reg;
#pragma unroll
      for (int nf = 0; nf < 4; nf++) {
        const int col = n0 + wn * 64 + nf * 16 + lr;
        float v = acc[mf][nf][reg];
        if (bias) v += bias[col];
        if (OUT_BF16) ((unsigned short*)Cv)[(size_t)row * N + col] = f2bf(v);
        else          ((float*)Cv)[(size_t)row * N + col] = v;
      }
    }
}

// ---------------- conv1 (3x3, 32->32ch) -> y1 [img][pix][32] + IN1 partials ----
// grid 2048 = (img<<1)|half; 512 thr; LDS 44,032 B.
__global__ __launch_bounds__(512, 4) void conv1_k3(
    const float* __restrict__ rpe, const unsigned short* __restrict__ w1frag,
    unsigned short* __restrict__ y1g, float* __restrict__ partialS)
{
  extern __shared__ __align__(16) char smem[];
  unsigned short* inH = (unsigned short*)smem;            // 4 x 5472 halves
  float* statA = (float*)(smem + 43776);                  // 64

  const int tid = threadIdx.x;
  const int wv = tid >> 6, ln = tid & 63;
  const int lr = ln & 15, lq = ln >> 4;
  const int img = blockIdx.x >> 1, h = blockIdx.x & 1;

  if (tid < 64) statA[tid] = 0.f;

  // stage input band (19 rows = 684 px, channel-major groups)
  const float* src = rpe + (size_t)(((img >> 5) + 2) * 36 + (img & 31) + 2) * 41472
                   + h * 19584;
  for (int t = tid; t < 5472; t += 512) {
    int pix = t >> 3, dq = (t & 7) << 2;
    float4 v = *(const float4*)(src + t * 4);
    __half2 h0 = __floats2half2_rn(v.x, v.y);
    __half2 h1 = __floats2half2_rn(v.z, v.w);
    uint2 u; u.x = __builtin_bit_cast(unsigned, h0); u.y = __builtin_bit_cast(unsigned, h1);
    *(uint2*)&inH[(dq >> 3) * 5472 + pix * 8 + (dq & 7)] = u;
  }
  // fragments: one contiguous 1KB wave-load per (ct,tap); L1-resident after blk 0
  f16x8 w1f[2][9];
#pragma unroll
  for (int ct = 0; ct < 2; ct++)
#pragma unroll
    for (int tap = 0; tap < 9; tap++)
      w1f[ct][tap] = *(const f16x8*)&w1frag[((tap * 2 + ct) * 64 + ln) * 8];
  __syncthreads();

  constexpr int OFF1[9] = {0, 8, 16, 288, 296, 304, 576, 584, 592};
  // y1 pixel-major: y1[img][pix][32]; lane pair (ch 2lr,2lr+1) -> contiguous 4B;
  // 16 lanes of a quarter -> one contiguous 64B segment.
  unsigned short* ybase = y1g + (size_t)img * 36992 + 2 * lr;
  const unsigned short* inAg = inH + lq * 5472;
  float s0 = 0.f, q0 = 0.f, s1 = 0.f, q1 = 0.f;
  for (int t = wv; t < 37; t += 8) {
    int m = t * 16 + lr;
    int ms = m < 577 ? m : 577;
    const unsigned short* ab = inAg + ((ms / 34) * 36 + (ms % 34)) * 8;
    f32x4 c0 = {0.f, 0.f, 0.f, 0.f}, c1v = {0.f, 0.f, 0.f, 0.f};
#pragma unroll
    for (int tap = 0; tap < 9; tap++) {
      f16x8 av = *(const f16x8*)(ab + OFF1[tap]);
      c0  = __builtin_amdgcn_mfma_f32_16x16x32_f16(av, w1f[0][tap], c0, 0, 0, 0);
      c1v = __builtin_amdgcn_mfma_f32_16x16x32_f16(av, w1f[1][tap], c1v, 0, 0, 0);
    }
#pragma unroll
    for (int r = 0; r < 4; r++) {
      int mo = t * 16 + lq * 4 + r;
      if (mo < 578) {
        float v0 = c0[r], v1 = c1v[r];   // channels 2*lr, 2*lr+1
        unsigned u = (unsigned)__half_as_ushort(__float2half(v0))
                   | ((unsigned)__half_as_ushort(__float2half(v1)) << 16);
        *(unsigned*)(ybase + (size_t)(h * 578 + mo) * 32) = u;
        s0 += v0; q0 += v0 * v0; s1 += v1; q1 += v1 * v1;
      }
    }
  }
#pragma unroll
  for (int off = 16; off < 64; off <<= 1) {
    s0 += __shfl_xor(s0, off); q0 += __shfl_xor(q0, off);
    s1 += __shfl_xor(s1, off); q1 += __shfl_xor(q1, off);
  }
  if (ln < 16) {
    atomicAdd(&statA[ln], s0);      atomicAdd(&statA[16 + ln], q0);
    atomicAdd(&statA[32 + ln], s1); atomicAdd(&statA[48 + ln], q1);
  }
  __syncthreads();
  if (tid < 64) partialS[(size_t)img * 128 + h * 64 + tid] = statA[tid];
}

// ------- conv2_k3: normalize+relu fused into transpose-staging; conv2+IN2+sig --
// grid 1024 (one image); 512 thr; LDS 74,368 B (yB group stride 9256 halves:
// word stride mod 32 = 20 -> staging b128 writes conflict-free).
__global__ __launch_bounds__(512, 4) void conv2_k3(
    const unsigned short* __restrict__ y1g, const unsigned short* __restrict__ w2frag,
    const float* __restrict__ partialS,
    const float* __restrict__ g1, const float* __restrict__ b1,
    const float* __restrict__ g2, const float* __restrict__ b2,
    float* __restrict__ wout)
{
  extern __shared__ __align__(16) char smem[];
  unsigned short* yB = (unsigned short*)smem;             // [g][1156][8], stride 9256
  float* statA = (float*)(smem + 74048);                  // 16 (IN2)
  float* aL    = statA + 16;                              // 32
  float* cL    = aL + 32;                                 // 32
  float* transF = (float*)smem;                           // overlay [8][1032]

  const int tid = threadIdx.x;
  const int wv = tid >> 6, ln = tid & 63;
  const int lr = ln & 15, lq = ln >> 4;
  const int p = blockIdx.x;

  if (tid < 16) statA[tid] = 0.f;
  if (tid < 32) {
    int cti = tid >> 4, lri = tid & 15;           // ch = 2*lri + cti
    const float* P = partialS + (size_t)p * 128;
    float s = P[cti * 32 + lri]      + P[64 + cti * 32 + lri];
    float q = P[cti * 32 + 16 + lri] + P[64 + cti * 32 + 16 + lri];
    int ch = 2 * lri + cti;
    float mu = s * (1.f / 1156.f);
    float var = q * (1.f / 1156.f) - mu * mu;
    float a_ = rsqrtf(var + 1e-5f) * g1[ch];
    aL[ch] = a_; cL[ch] = b1[ch] - mu * a_;
  }
  __syncthreads();

  // stage y1 [pix][32] -> LDS [g][pix][8] with FUSED normalize + relu.
  // read: consecutive tids -> consecutive 16B -> fully coalesced.
  const unsigned short* srcY = y1g + (size_t)p * 36992;
  for (int t = tid; t < 4624; t += 512) {
    int pix = t >> 2, g = t & 3;
    f16x8 raw = *(const f16x8*)&srcY[pix * 32 + g * 8];
    f16x8 outv;
#pragma unroll
    for (int e = 0; e < 8; e++) {
      float v = (float)raw[e];
      outv[e] = (_Float16)fmaxf(v * aL[g * 8 + e] + cL[g * 8 + e], 0.f);
    }
    *(f16x8*)&yB[g * 9256 + pix * 8] = outv;
  }
  __syncthreads();

  // conv2: fragments from global (1KB wave-loads), 8 tiles/wave, z in regs
  f16x8 w2f[9];
#pragma unroll
  for (int tap = 0; tap < 9; tap++)
    w2f[tap] = *(const f16x8*)&w2frag[(tap * 64 + ln) * 8];

  constexpr int OFF2[9] = {0, 8, 16, 272, 280, 288, 544, 552, 560};
  const unsigned short* yBg = yB + lq * 9256;
  f32x4 zsave[8];
  float s2 = 0.f, q2 = 0.f;
#pragma unroll
  for (int i = 0; i < 8; i++) {
    int t = wv + i * 8;
    int m = t * 16 + lr;
    const unsigned short* ab = yBg + ((m >> 5) * 34 + (m & 31)) * 8;
    f32x4 cc = {0.f, 0.f, 0.f, 0.f};
#pragma unroll
    for (int tap = 0; tap < 9; tap++) {
      f16x8 av = *(const f16x8*)(ab + OFF2[tap]);
      cc = __builtin_amdgcn_mfma_f32_16x16x32_f16(av, w2f[tap], cc, 0, 0, 0);
    }
    zsave[i] = cc;
#pragma unroll
    for (int r = 0; r < 4; r++) { s2 += cc[r]; q2 += cc[r] * cc[r]; }
  }
#pragma unroll
  for (int off = 16; off < 64; off <<= 1) {
    s2 += __shfl_xor(s2, off); q2 += __shfl_xor(q2, off);
  }
  if (ln < 8) { atomicAdd(&statA[ln], s2); atomicAdd(&statA[8 + ln], q2); }
  __syncthreads();   // conv2 reads of yB complete -> transF overlay safe

  if (lr < 8) {
#pragma unroll
    for (int i = 0; i < 8; i++) {
      int t = wv + i * 8;
#pragma unroll
      for (int r = 0; r < 4; r++)
        transF[lr * 1032 + t * 16 + lq * 4 + r] = zsave[i][r];
    }
  }
  if (tid < 8) {
    float s = statA[tid], q = statA[8 + tid];
    float mu = s * (1.f / 1024.f);
    float var = q * (1.f / 1024.f) - mu * mu;
    float a_ = rsqrtf(var + 1e-5f) * g2[tid];
    aL[tid] = a_; cL[tid] = b2[tid] - mu * a_;
  }
  __syncthreads();

  for (int idx = tid; idx < 2048; idx += 512) {
    int oc = idx >> 8, p4 = (idx & 255) << 2;
    float4 v = *(const float4*)&transF[oc * 1032 + p4];
    float a_ = aL[oc], c_ = cL[oc];
    float4 o;
    o.x = 1.f / (1.f + __expf(-(v.x * a_ + c_)));
    o.y = 1.f / (1.f + __expf(-(v.y * a_ + c_)));
    o.z = 1.f / (1.f + __expf(-(v.z * a_ + c_)));
    o.w = 1.f / (1.f + __expf(-(v.w * a_ + c_)));
    *(float4*)(wout + ((size_t)oc << 20) + ((size_t)p << 10) + p4) = o;
  }
}

// ---------------- fused attention, bf16 MFMA 16x16x32 -------------------------
__global__ __launch_bounds__(256) void attn_kernel(
    const unsigned short* __restrict__ qkv,  // bf16 bits [8192][1536]
    const float* __restrict__ wppe,          // [8][1024][1024]
    float* __restrict__ oh)                  // [8192][512] = (b,n,h,d)
{
  __shared__ __align__(16) unsigned short k_lds[64 * 72];
  __shared__ __align__(16) unsigned short v_lds[64 * 72]; // transposed [d][m ^ swz]
  __shared__ __align__(16) unsigned short p_lds[4 * 16 * 72];
  const int tid = threadIdx.x;
  const int wv = tid >> 6, ln = tid & 63;
  const int lr = ln & 15, lq = ln >> 4;
  const int b = blockIdx.y >> 3, h = blockIdx.y & 7;
  const int n0 = blockIdx.x << 6;

  const size_t qoff = (size_t)((b << 10) + n0 + (wv << 4) + lr) * 1536 + (h << 6);
  bf16x8 qf0 = *(const bf16x8*)(qkv + qoff + lq * 8);
  bf16x8 qf1 = *(const bf16x8*)(qkv + qoff + 32 + lq * 8);

  f32x4 acc[4];
#pragma unroll
  for (int dt = 0; dt < 4; dt++) acc[dt] = (f32x4){0.f, 0.f, 0.f, 0.f};
  float den[4] = {0.f, 0.f, 0.f, 0.f};
  const float* wp = wppe + ((size_t)h << 20);

  for (int m0 = 0; m0 < 1024; m0 += 64) {
    __syncthreads();
    for (int t = tid; t < 512; t += 256) {
      int m = t >> 3, dq = t & 7;
      const unsigned short* kr = qkv + (size_t)((b << 10) + m0 + m) * 1536 + 512 + (h << 6) + dq * 8;
      *(uint4*)&k_lds[m * 72 + dq * 8] = *(const uint4*)kr;
      uint4 vvv = *(const uint4*)(kr + 512);
      unsigned short tmp[8];
      *(uint4*)tmp = vvv;
#pragma unroll
      for (int i = 0; i < 8; i++) {
        int d = dq * 8 + i;
        v_lds[d * 72 + (m ^ (((d >> 3) & 7) << 3))] = tmp[i];
      }
    }
    __syncthreads();

    f32x4 s[4];
#pragma unroll
    for (int mt = 0; mt < 4; mt++) {
      const unsigned short* kb = &k_lds[(mt * 16 + lr) * 72 + lq * 8];
      f32x4 cz = (f32x4){0.f, 0.f, 0.f, 0.f};
      cz = __builtin_amdgcn_mfma_f32_16x16x32_bf16(qf0, *(const bf16x8*)kb, cz, 0, 0, 0);
      cz = __builtin_amdgcn_mfma_f32_16x16x32_bf16(qf1, *(const bf16x8*)(kb + 32), cz, 0, 0, 0);
      s[mt] = cz;
    }
#pragma unroll
    for (int mt = 0; mt < 4; mt++)
#pragma unroll
      for (int reg = 0; reg < 4; reg++) {
        int rrow = lq * 4 + reg;
        float wvl = wp[(size_t)(n0 + (wv << 4) + rrow) * 1024 + (m0 + mt * 16 + lr)];
        float pv = wvl * __expf(s[mt][reg] * 0.125f);
        den[reg] += pv;
        p_lds[((wv << 4) + rrow) * 72 + mt * 16 + lr] = f2bf(pv);
      }
    const unsigned short* pb = &p_lds[((wv << 4) + lr) * 72];
    bf16x8 pa0 = *(const bf16x8*)(pb + lq * 8);
    bf16x8 pa1 = *(const bf16x8*)(pb + 32 + lq * 8);
#pragma unroll
    for (int dt = 0; dt < 4; dt++) {
      int d = dt * 16 + lr;
      int sw = ((d >> 3) & 7) << 3;
      const unsigned short* vb = &v_lds[d * 72];
      acc[dt] = __builtin_amdgcn_mfma_f32_16x16x32_bf16(pa0, *(const bf16x8*)(vb + ((lq * 8) ^ sw)), acc[dt], 0, 0, 0);
      acc[dt] = __builtin_amdgcn_mfma_f32_16x16x32_bf16(pa1, *(const bf16x8*)(vb + ((32 + lq * 8) ^ sw)), acc[dt], 0, 0, 0);
    }
  }
#pragma unroll
  for (int off = 1; off < 16; off <<= 1)
#pragma unroll
    for (int reg = 0; reg < 4; reg++) den[reg] += __shfl_xor(den[reg], off);
#pragma unroll
  for (int dt = 0; dt < 4; dt++)
#pragma unroll
    for (int reg = 0; reg < 4; reg++) {
      size_t row = (size_t)((b << 10) + n0 + (wv << 4) + lq * 4 + reg);
      oh[row * 512 + (h << 6) + dt * 16 + lr] = acc[dt][reg] / den[reg];
    }
}

// ---------------------------------------------------------------------------
extern "C" void kernel_launch(void* const* d_in, const int* in_sizes, int n_in,
                              void* d_out, int out_size, void* d_ws, size_t ws_size,
                              hipStream_t stream) {
  (void)in_sizes; (void)n_in; (void)out_size; (void)ws_size;
  const float* x     = (const float*)d_in[0];
  const float* rpe   = (const float*)d_in[1];
  const float* wqkv  = (const float*)d_in[2];
  const float* wproj = (const float*)d_in[3];
  const float* bproj = (const float*)d_in[4];
  const float* c1w   = (const float*)d_in[5];
  // d_in[6] = c1b: cancels exactly in the following instance-norm
  const float* g1w   = (const float*)d_in[7];
  const float* g1b   = (const float*)d_in[8];
  const float* c2w   = (const float*)d_in[9];
  // d_in[10] = c2b: cancels likewise
  const float* g2w   = (const float*)d_in[11];
  const float* g2b   = (const float*)d_in[12];
  float* out = (float*)d_out;

  char* ws = (char*)d_ws;
  unsigned short* qkv_bf = (unsigned short*)ws;             // 25,165,824 B
  float* wppe = (float*)(ws + 25165824);                    // 33,554,432 B
  unsigned short* y1g = (unsigned short*)(ws + 58720256);   // 75,759,616 B
  float* ohb = (float*)(ws + 58720256);                     // overlays y1g (dead after conv2_k3)
  unsigned short* w1frag = (unsigned short*)(ws + 134479872); // 18,432 B
  unsigned short* w2frag = (unsigned short*)(ws + 134498304); // 9,216 B
  float* partialS = (float*)(ws + 134507520);               // 524,288 B

  // 0) bake weight fragments
  wprep<<<36, 256, 0, stream>>>(c1w, c2w, w1frag, w2frag);

  // 1) qkv = x @ wqkv^T  -> bf16 (f16 MFMA)
  gemm_f16_bt<true><<<dim3(12, 64), 256, 0, stream>>>(x, wqkv, qkv_bf, nullptr, 8192, 1536, 512);

  // 2) conv1 -> y1g [img][pix][32] + IN1 partials
  const int lds1 = 44032;
  hipFuncSetAttribute(reinterpret_cast<const void*>(&conv1_k3),
                      hipFuncAttributeMaxDynamicSharedMemorySize, lds1);
  conv1_k3<<<2048, 512, lds1, stream>>>(rpe, w1frag, y1g, partialS);

  // 3) IN1+relu (fused in transpose-staging) + conv2 + IN2 + sigmoid -> w
  const int lds2 = 74368;
  hipFuncSetAttribute(reinterpret_cast<const void*>(&conv2_k3),
                      hipFuncAttributeMaxDynamicSharedMemorySize, lds2);
  conv2_k3<<<1024, 512, lds2, stream>>>(y1g, w2frag, partialS, g1w, g1b, g2w, g2b, wppe);

  // 4) fused attention
  attn_kernel<<<dim3(16, 64), 256, 0, stream>>>(qkv_bf, wppe, ohb);

  // 5) out = oh @ wproj^T + bproj (f16 MFMA)
  gemm_f16_bt<false><<<dim3(4, 64), 256, 0, stream>>>(ohb, wproj, out, bproj, 8192, 512, 512);
}

// Round 12
// 205.709 us; speedup vs baseline: 1.4718x; 1.0992x over previous
//
#include <hip/hip_runtime.h>
#include <hip/hip_fp16.h>

// MPA_16698832847132 — round 12: revert to r6-fused conv (measured best: 137µs
// vs split's ~150) + two targeted fixes:
//  (a) 2-tile unroll in conv1/conv2 -> 4 independent MFMA chains per wave
//      (was 2 chains of 9 dependent MFMAs = latency-bound at 9% MfmaUtil),
//  (b) weight fragments pre-baked by wprep, loaded from global (kills the
//      stride-40 LDS re-read conflicts: r7-bench's remaining 1.25e7 cycles).
// Workspace: qkv bf16 @0 | w f32 @25,165,824 | ohb @58,720,256 |
//            w1frag @75,497,472 | w2frag @75,515,904

typedef __attribute__((ext_vector_type(8))) short bf16x8;
typedef __attribute__((ext_vector_type(8))) _Float16 f16x8;
typedef __attribute__((ext_vector_type(4))) float f32x4;

__device__ __forceinline__ unsigned short f2bf(float f) {
  unsigned u = __builtin_bit_cast(unsigned, f);
  u += 0x7FFFu + ((u >> 16) & 1u);
  return (unsigned short)(u >> 16);
}

// ---------------- weight fragment prep (once per launch) -----------------------
__global__ __launch_bounds__(256) void wprep(
    const float* __restrict__ c1w, const float* __restrict__ c2w,
    unsigned short* __restrict__ w1frag, unsigned short* __restrict__ w2frag)
{
  int t = blockIdx.x * 256 + threadIdx.x;
  if (t < 9216) {
    int j = t & 7, ln = (t >> 3) & 63, ctap = t >> 9;
    int tap = ctap >> 1, ct = ctap & 1;
    int oc = 2 * (ln & 15) + ct, ic = (ln >> 4) * 8 + j;
    w1frag[t] = __half_as_ushort(__float2half(c1w[(oc * 32 + ic) * 9 + tap]));
  }
  if (t < 4608) {
    int j = t & 7, ln = (t >> 3) & 63, tap = t >> 9;
    int oc = (ln & 15) & 7, ic = (ln >> 4) * 8 + j;
    w2frag[t] = __half_as_ushort(__float2half(c2w[(oc * 32 + ic) * 9 + tap]));
  }
}

// ---------------- C[M][N] = A[M][K] * B[N][K]^T (+bias), f16 MFMA --------------
template<bool OUT_BF16>
__global__ __launch_bounds__(256) void gemm_f16_bt(
    const float* __restrict__ A, const float* __restrict__ B,
    void* __restrict__ Cv, const float* __restrict__ bias,
    int M, int N, int K)
{
  __shared__ __align__(16) _Float16 As[128 * 40];
  __shared__ __align__(16) _Float16 Bs[128 * 40];
  const int tid = threadIdx.x;
  const int wv = tid >> 6, ln = tid & 63, lr = ln & 15, lq = ln >> 4;
  const int wm = wv >> 1, wn = wv & 1;
  const int m0 = blockIdx.y * 128, n0 = blockIdx.x * 128;

  f32x4 acc[4][4];
#pragma unroll
  for (int i = 0; i < 4; i++)
#pragma unroll
    for (int j = 0; j < 4; j++) acc[i][j] = (f32x4){0.f, 0.f, 0.f, 0.f};

  const int sr = tid >> 1, sk = (tid & 1) * 16;
  const float* Ap = A + (size_t)(m0 + sr) * K + sk;
  const float* Bp = B + (size_t)(n0 + sr) * K + sk;

  for (int k0 = 0; k0 < K; k0 += 32) {
    float4 av0 = *(const float4*)(Ap + k0);
    float4 av1 = *(const float4*)(Ap + k0 + 4);
    float4 av2 = *(const float4*)(Ap + k0 + 8);
    float4 av3 = *(const float4*)(Ap + k0 + 12);
    float4 bv0 = *(const float4*)(Bp + k0);
    float4 bv1 = *(const float4*)(Bp + k0 + 4);
    float4 bv2 = *(const float4*)(Bp + k0 + 8);
    float4 bv3 = *(const float4*)(Bp + k0 + 12);
    __syncthreads();
    {
      f16x8 p0, p1, r0, r1;
      p0[0]=(_Float16)av0.x; p0[1]=(_Float16)av0.y; p0[2]=(_Float16)av0.z; p0[3]=(_Float16)av0.w;
      p0[4]=(_Float16)av1.x; p0[5]=(_Float16)av1.y; p0[6]=(_Float16)av1.z; p0[7]=(_Float16)av1.w;
      p1[0]=(_Float16)av2.x; p1[1]=(_Float16)av2.y; p1[2]=(_Float16)av2.z; p1[3]=(_Float16)av2.w;
      p1[4]=(_Float16)av3.x; p1[5]=(_Float16)av3.y; p1[6]=(_Float16)av3.z; p1[7]=(_Float16)av3.w;
      r0[0]=(_Float16)bv0.x; r0[1]=(_Float16)bv0.y; r0[2]=(_Float16)bv0.z; r0[3]=(_Float16)bv0.w;
      r0[4]=(_Float16)bv1.x; r0[5]=(_Float16)bv1.y; r0[6]=(_Float16)bv1.z; r0[7]=(_Float16)bv1.w;
      r1[0]=(_Float16)bv2.x; r1[1]=(_Float16)bv2.y; r1[2]=(_Float16)bv2.z; r1[3]=(_Float16)bv2.w;
      r1[4]=(_Float16)bv3.x; r1[5]=(_Float16)bv3.y; r1[6]=(_Float16)bv3.z; r1[7]=(_Float16)bv3.w;
      *(f16x8*)&As[sr * 40 + sk] = p0;
      *(f16x8*)&As[sr * 40 + sk + 8] = p1;
      *(f16x8*)&Bs[sr * 40 + sk] = r0;
      *(f16x8*)&Bs[sr * 40 + sk + 8] = r1;
    }
    __syncthreads();
    f16x8 af[4], bf[4];
#pragma unroll
    for (int mf = 0; mf < 4; mf++)
      af[mf] = *(const f16x8*)&As[(wm * 64 + mf * 16 + lr) * 40 + lq * 8];
#pragma unroll
    for (int nf = 0; nf < 4; nf++)
      bf[nf] = *(const f16x8*)&Bs[(wn * 64 + nf * 16 + lr) * 40 + lq * 8];
#pragma unroll
    for (int mf = 0; mf < 4; mf++)
#pragma unroll
      for (int nf = 0; nf < 4; nf++)
        acc[mf][nf] = __builtin_amdgcn_mfma_f32_16x16x32_f16(af[mf], bf[nf], acc[mf][nf], 0, 0, 0);
  }

#pragma unroll
  for (int mf = 0; mf < 4; mf++)
#pragma unroll
    for (int reg = 0; reg < 4; reg++) {
      const int row = m0 + wm * 64 + mf * 16 + lq * 4 + reg;
#pragma unroll
      for (int nf = 0; nf < 4; nf++) {
        const int col = n0 + wn * 64 + nf * 16 + lr;
        float v = acc[mf][nf][reg];
        if (bias) v += bias[col];
        if (OUT_BF16) ((unsigned short*)Cv)[(size_t)row * N + col] = f2bf(v);
        else          ((float*)Cv)[(size_t)row * N + col] = v;
      }
    }
}

// ---------------- fused conv1+IN1+relu+conv2+IN2+sigmoid, f16 MFMA -------------
// One image per block (grid 1024), 1024 threads = 16 waves (4/SIMD).
// LDS: inA[4][1296][8] @0 (82,944) | yB[4][1156][8] @82,944 (73,984)
//      statA f32[64] @156,928 | aL/cL f32[32+32] @157,184 -> total 157,440
// Overlays: transF f32[8][1032] on inA (conv2/sigmoid phase).
// Weight fragments from pre-baked global arrays (no LDS weight staging).
__global__ __launch_bounds__(1024, 1) void conv_fused3(
    const float* __restrict__ rpe,
    const unsigned short* __restrict__ w1frag, const unsigned short* __restrict__ w2frag,
    const float* __restrict__ g1, const float* __restrict__ b1,
    const float* __restrict__ g2, const float* __restrict__ b2,
    float* __restrict__ wout)
{
  extern __shared__ __align__(16) char smem[];
  unsigned short* inA = (unsigned short*)smem;              // 4 x 10368 halves
  unsigned short* yB  = (unsigned short*)(smem + 82944);    // 4 x 9248 halves
  float* statA = (float*)(smem + 156928);                   // 64
  float* aL    = (float*)(smem + 157184);                   // 32
  float* cL    = aL + 32;                                   // 32
  float* transF = (float*)smem;                             // overlay [8][1032]

  const int tid = threadIdx.x;
  const int wv = tid >> 6, ln = tid & 63;
  const int lr = ln & 15, lq = ln >> 4;
  const int p = blockIdx.x;

  if (tid < 64) statA[tid] = 0.f;

  // ---- stage input: rpe crop -> LDS f16 channel-major [g][pix][8]
  const float* src = rpe + (size_t)(((p >> 5) + 2) * 36 + (p & 31) + 2) * 41472;
  for (int t = tid; t < 10368; t += 1024) {
    int pix = t >> 3, dq = (t & 7) << 2;
    float4 v = *(const float4*)(src + pix * 32 + dq);
    __half2 h0 = __floats2half2_rn(v.x, v.y);
    __half2 h1 = __floats2half2_rn(v.z, v.w);
    uint2 u; u.x = __builtin_bit_cast(unsigned, h0); u.y = __builtin_bit_cast(unsigned, h1);
    *(uint2*)&inA[(dq >> 3) * 10368 + pix * 8 + (dq & 7)] = u;
  }

  // ---- w1 fragments from global (contiguous 1KB wave-loads, L1-resident)
  f16x8 w1f[2][9];
#pragma unroll
  for (int ct = 0; ct < 2; ct++)
#pragma unroll
    for (int tap = 0; tap < 9; tap++)
      w1f[ct][tap] = *(const f16x8*)&w1frag[((tap * 2 + ct) * 64 + ln) * 8];
  __syncthreads();

  // ---- conv1: 2-tile unrolled pairs (tiles 0..63, all rows valid) + tail 64..72
  constexpr int OFF1[9] = {0, 8, 16, 288, 296, 304, 576, 584, 592};
  const unsigned short* inAg = inA + lq * 10368;
  float s0 = 0.f, q0 = 0.f, s1 = 0.f, q1 = 0.f;
  for (int t0 = wv; t0 < 64; t0 += 32) {
    const int tA = t0, tB = t0 + 16;
    const int mA = tA * 16 + lr, mB = tB * 16 + lr;
    const unsigned short* abA = inAg + ((mA / 34) * 36 + (mA % 34)) * 8;
    const unsigned short* abB = inAg + ((mB / 34) * 36 + (mB % 34)) * 8;
    f32x4 cA0 = {0.f,0.f,0.f,0.f}, cA1 = {0.f,0.f,0.f,0.f};
    f32x4 cB0 = {0.f,0.f,0.f,0.f}, cB1 = {0.f,0.f,0.f,0.f};
#pragma unroll
    for (int tap = 0; tap < 9; tap++) {
      f16x8 avA = *(const f16x8*)(abA + OFF1[tap]);
      f16x8 avB = *(const f16x8*)(abB + OFF1[tap]);
      cA0 = __builtin_amdgcn_mfma_f32_16x16x32_f16(avA, w1f[0][tap], cA0, 0, 0, 0);
      cA1 = __builtin_amdgcn_mfma_f32_16x16x32_f16(avA, w1f[1][tap], cA1, 0, 0, 0);
      cB0 = __builtin_amdgcn_mfma_f32_16x16x32_f16(avB, w1f[0][tap], cB0, 0, 0, 0);
      cB1 = __builtin_amdgcn_mfma_f32_16x16x32_f16(avB, w1f[1][tap], cB1, 0, 0, 0);
    }
#pragma unroll
    for (int r = 0; r < 4; r++) {
      int moA = tA * 16 + lq * 4 + r;
      float v0 = cA0[r], v1 = cA1[r];
      unsigned u = (unsigned)__half_as_ushort(__float2half(v0))
                 | ((unsigned)__half_as_ushort(__float2half(v1)) << 16);
      *(unsigned*)&yB[(lr >> 2) * 9248 + moA * 8 + ((lr * 2) & 7)] = u;
      s0 += v0; q0 += v0 * v0; s1 += v1; q1 += v1 * v1;
      int moB = tB * 16 + lq * 4 + r;
      float w0 = cB0[r], w1 = cB1[r];
      unsigned u2 = (unsigned)__half_as_ushort(__float2half(w0))
                  | ((unsigned)__half_as_ushort(__float2half(w1)) << 16);
      *(unsigned*)&yB[(lr >> 2) * 9248 + moB * 8 + ((lr * 2) & 7)] = u2;
      s0 += w0; q0 += w0 * w0; s1 += w1; q1 += w1 * w1;
    }
  }
  if (wv < 9) {                       // tail tiles 64..72 (tile 72 partial)
    int t = wv + 64;
    int m = t * 16 + lr;
    int ms = m < 1155 ? m : 1155;
    const unsigned short* ab = inAg + ((ms / 34) * 36 + (ms % 34)) * 8;
    f32x4 c0 = {0.f,0.f,0.f,0.f}, c1v = {0.f,0.f,0.f,0.f};
#pragma unroll
    for (int tap = 0; tap < 9; tap++) {
      f16x8 av = *(const f16x8*)(ab + OFF1[tap]);
      c0  = __builtin_amdgcn_mfma_f32_16x16x32_f16(av, w1f[0][tap], c0, 0, 0, 0);
      c1v = __builtin_amdgcn_mfma_f32_16x16x32_f16(av, w1f[1][tap], c1v, 0, 0, 0);
    }
#pragma unroll
    for (int r = 0; r < 4; r++) {
      int mo = t * 16 + lq * 4 + r;
      if (mo < 1156) {
        float v0 = c0[r], v1 = c1v[r];
        unsigned u = (unsigned)__half_as_ushort(__float2half(v0))
                   | ((unsigned)__half_as_ushort(__float2half(v1)) << 16);
        *(unsigned*)&yB[(lr >> 2) * 9248 + mo * 8 + ((lr * 2) & 7)] = u;
        s0 += v0; q0 += v0 * v0; s1 += v1; q1 += v1 * v1;
      }
    }
  }
#pragma unroll
  for (int off = 16; off < 64; off <<= 1) {
    s0 += __shfl_xor(s0, off); q0 += __shfl_xor(q0, off);
    s1 += __shfl_xor(s1, off); q1 += __shfl_xor(q1, off);
  }
  if (ln < 16) {
    atomicAdd(&statA[ln], s0);      atomicAdd(&statA[16 + ln], q0);
    atomicAdd(&statA[32 + ln], s1); atomicAdd(&statA[48 + ln], q1);
  }
  __syncthreads();
  if (tid < 32) {
    int cti = tid >> 4, lri = tid & 15;   // ch = 2*lri + cti
    float s = statA[cti * 32 + lri];
    float q = statA[cti * 32 + 16 + lri];
    int ch = 2 * lri + cti;
    float mu = s * (1.f / 1156.f);
    float var = q * (1.f / 1156.f) - mu * mu;
    float a_ = rsqrtf(var + 1e-5f) * g1[ch];
    aL[ch] = a_; cL[ch] = b1[ch] - mu * a_;
  }
  if (tid < 16) statA[tid] = 0.f;  // IN2 slots (same-thread program order safe)
  __syncthreads();

  // ---- normalize + relu RMW on yB (channel-major)
  {
    int g = tid >> 8, ocb = g * 8;
    unsigned short* yg = yB + g * 9248;
    for (int pix = (tid & 255); pix < 1156; pix += 256) {
      f16x8 raw = *(const f16x8*)&yg[pix * 8];
      f16x8 outv;
#pragma unroll
      for (int e = 0; e < 8; e++) {
        float v = (float)raw[e];
        outv[e] = (_Float16)fmaxf(v * aL[ocb + e] + cL[ocb + e], 0.f);
      }
      *(f16x8*)&yg[pix * 8] = outv;
    }
  }
  __syncthreads();

  // ---- conv2: fragments from global; 2-tile pairs (tiles wv..wv+48, exact)
  f16x8 w2f[9];
#pragma unroll
  for (int tap = 0; tap < 9; tap++)
    w2f[tap] = *(const f16x8*)&w2frag[(tap * 64 + ln) * 8];

  constexpr int OFF2[9] = {0, 8, 16, 272, 280, 288, 544, 552, 560};
  const unsigned short* yBg = yB + lq * 9248;
  float s2 = 0.f, q2 = 0.f;
#pragma unroll
  for (int t0 = 0; t0 < 2; t0++) {
    const int tA = wv + t0 * 32, tB = tA + 16;
    const int mA = tA * 16 + lr, mB = tB * 16 + lr;
    const unsigned short* abA = yBg + ((mA >> 5) * 34 + (mA & 31)) * 8;
    const unsigned short* abB = yBg + ((mB >> 5) * 34 + (mB & 31)) * 8;
    f32x4 ccA = {0.f,0.f,0.f,0.f}, ccB = {0.f,0.f,0.f,0.f};
#pragma unroll
    for (int tap = 0; tap < 9; tap++) {
      f16x8 avA = *(const f16x8*)(abA + OFF2[tap]);
      f16x8 avB = *(const f16x8*)(abB + OFF2[tap]);
      ccA = __builtin_amdgcn_mfma_f32_16x16x32_f16(avA, w2f[tap], ccA, 0, 0, 0);
      ccB = __builtin_amdgcn_mfma_f32_16x16x32_f16(avB, w2f[tap], ccB, 0, 0, 0);
    }
#pragma unroll
    for (int r = 0; r < 4; r++) {
      float vA = ccA[r], vB = ccB[r];
      s2 += vA + vB; q2 += vA * vA + vB * vB;
      if (lr < 8) {
        transF[lr * 1032 + tA * 16 + lq * 4 + r] = vA;
        transF[lr * 1032 + tB * 16 + lq * 4 + r] = vB;
      }
    }
  }
#pragma unroll
  for (int off = 16; off < 64; off <<= 1) {
    s2 += __shfl_xor(s2, off); q2 += __shfl_xor(q2, off);
  }
  if (ln < 8) { atomicAdd(&statA[ln], s2); atomicAdd(&statA[8 + ln], q2); }
  __syncthreads();
  if (tid < 8) {
    float s = statA[tid], q = statA[8 + tid];
    float mu = s * (1.f / 1024.f);
    float var = q * (1.f / 1024.f) - mu * mu;
    float a_ = rsqrtf(var + 1e-5f) * g2[tid];
    aL[tid] = a_; cL[tid] = b2[tid] - mu * a_;
  }
  __syncthreads();

  // ---- sigmoid + coalesced store: wout[oc][p][pix]
  for (int idx = tid; idx < 2048; idx += 1024) {
    int oc = idx >> 8, p4 = (idx & 255) << 2;
    float4 v = *(const float4*)&transF[oc * 1032 + p4];
    float a_ = aL[oc], c_ = cL[oc];
    float4 o;
    o.x = 1.f / (1.f + __expf(-(v.x * a_ + c_)));
    o.y = 1.f / (1.f + __expf(-(v.y * a_ + c_)));
    o.z = 1.f / (1.f + __expf(-(v.z * a_ + c_)));
    o.w = 1.f / (1.f + __expf(-(v.w * a_ + c_)));
    *(float4*)(wout + ((size_t)oc << 20) + ((size_t)p << 10) + p4) = o;
  }
}

// ---------------- fused attention, bf16 MFMA 16x16x32 -------------------------
__global__ __launch_bounds__(256) void attn_kernel(
    const unsigned short* __restrict__ qkv,  // bf16 bits [8192][1536]
    const float* __restrict__ wppe,          // [8][1024][1024]
    float* __restrict__ oh)                  // [8192][512] = (b,n,h,d)
{
  __shared__ __align__(16) unsigned short k_lds[64 * 72];
  __shared__ __align__(16) unsigned short v_lds[64 * 72]; // transposed [d][m ^ swz]
  __shared__ __align__(16) unsigned short p_lds[4 * 16 * 72];
  const int tid = threadIdx.x;
  const int wv = tid >> 6, ln = tid & 63;
  const int lr = ln & 15, lq = ln >> 4;
  const int b = blockIdx.y >> 3, h = blockIdx.y & 7;
  const int n0 = blockIdx.x << 6;

  const size_t qoff = (size_t)((b << 10) + n0 + (wv << 4) + lr) * 1536 + (h << 6);
  bf16x8 qf0 = *(const bf16x8*)(qkv + qoff + lq * 8);
  bf16x8 qf1 = *(const bf16x8*)(qkv + qoff + 32 + lq * 8);

  f32x4 acc[4];
#pragma unroll
  for (int dt = 0; dt < 4; dt++) acc[dt] = (f32x4){0.f, 0.f, 0.f, 0.f};
  float den[4] = {0.f, 0.f, 0.f, 0.f};
  const float* wp = wppe + ((size_t)h << 20);

  for (int m0 = 0; m0 < 1024; m0 += 64) {
    __syncthreads();
    for (int t = tid; t < 512; t += 256) {
      int m = t >> 3, dq = t & 7;
      const unsigned short* kr = qkv + (size_t)((b << 10) + m0 + m) * 1536 + 512 + (h << 6) + dq * 8;
      *(uint4*)&k_lds[m * 72 + dq * 8] = *(const uint4*)kr;
      uint4 vvv = *(const uint4*)(kr + 512);
      unsigned short tmp[8];
      *(uint4*)tmp = vvv;
#pragma unroll
      for (int i = 0; i < 8; i++) {
        int d = dq * 8 + i;
        v_lds[d * 72 + (m ^ (((d >> 3) & 7) << 3))] = tmp[i];
      }
    }
    __syncthreads();

    f32x4 s[4];
#pragma unroll
    for (int mt = 0; mt < 4; mt++) {
      const unsigned short* kb = &k_lds[(mt * 16 + lr) * 72 + lq * 8];
      f32x4 cz = (f32x4){0.f, 0.f, 0.f, 0.f};
      cz = __builtin_amdgcn_mfma_f32_16x16x32_bf16(qf0, *(const bf16x8*)kb, cz, 0, 0, 0);
      cz = __builtin_amdgcn_mfma_f32_16x16x32_bf16(qf1, *(const bf16x8*)(kb + 32), cz, 0, 0, 0);
      s[mt] = cz;
    }
#pragma unroll
    for (int mt = 0; mt < 4; mt++)
#pragma unroll
      for (int reg = 0; reg < 4; reg++) {
        int rrow = lq * 4 + reg;
        float wvl = wp[(size_t)(n0 + (wv << 4) + rrow) * 1024 + (m0 + mt * 16 + lr)];
        float pv = wvl * __expf(s[mt][reg] * 0.125f);
        den[reg] += pv;
        p_lds[((wv << 4) + rrow) * 72 + mt * 16 + lr] = f2bf(pv);
      }
    const unsigned short* pb = &p_lds[((wv << 4) + lr) * 72];
    bf16x8 pa0 = *(const bf16x8*)(pb + lq * 8);
    bf16x8 pa1 = *(const bf16x8*)(pb + 32 + lq * 8);
#pragma unroll
    for (int dt = 0; dt < 4; dt++) {
      int d = dt * 16 + lr;
      int sw = ((d >> 3) & 7) << 3;
      const unsigned short* vb = &v_lds[d * 72];
      acc[dt] = __builtin_amdgcn_mfma_f32_16x16x32_bf16(pa0, *(const bf16x8*)(vb + ((lq * 8) ^ sw)), acc[dt], 0, 0, 0);
      acc[dt] = __builtin_amdgcn_mfma_f32_16x16x32_bf16(pa1, *(const bf16x8*)(vb + ((32 + lq * 8) ^ sw)), acc[dt], 0, 0, 0);
    }
  }
#pragma unroll
  for (int off = 1; off < 16; off <<= 1)
#pragma unroll
    for (int reg = 0; reg < 4; reg++) den[reg] += __shfl_xor(den[reg], off);
#pragma unroll
  for (int dt = 0; dt < 4; dt++)
#pragma unroll
    for (int reg = 0; reg < 4; reg++) {
      size_t row = (size_t)((b << 10) + n0 + (wv << 4) + lq * 4 + reg);
      oh[row * 512 + (h << 6) + dt * 16 + lr] = acc[dt][reg] / den[reg];
    }
}

// ---------------------------------------------------------------------------
extern "C" void kernel_launch(void* const* d_in, const int* in_sizes, int n_in,
                              void* d_out, int out_size, void* d_ws, size_t ws_size,
                              hipStream_t stream) {
  (void)in_sizes; (void)n_in; (void)out_size; (void)ws_size;
  const float* x     = (const float*)d_in[0];
  const float* rpe   = (const float*)d_in[1];
  const float* wqkv  = (const float*)d_in[2];
  const float* wproj = (const float*)d_in[3];
  const float* bproj = (const float*)d_in[4];
  const float* c1w   = (const float*)d_in[5];
  // d_in[6] = c1b: cancels exactly in the following instance-norm
  const float* g1w   = (const float*)d_in[7];
  const float* g1b   = (const float*)d_in[8];
  const float* c2w   = (const float*)d_in[9];
  // d_in[10] = c2b: cancels likewise
  const float* g2w   = (const float*)d_in[11];
  const float* g2b   = (const float*)d_in[12];
  float* out = (float*)d_out;

  char* ws = (char*)d_ws;
  unsigned short* qkv_bf = (unsigned short*)ws;             // 25,165,824 B
  float* wppe = (float*)(ws + 25165824);                    // 33,554,432 B
  float* ohb  = (float*)(ws + 58720256);                    // 16,777,216 B
  unsigned short* w1frag = (unsigned short*)(ws + 75497472); // 18,432 B
  unsigned short* w2frag = (unsigned short*)(ws + 75515904); // 9,216 B

  // 0) bake weight fragments
  wprep<<<36, 256, 0, stream>>>(c1w, c2w, w1frag, w2frag);

  // 1) qkv = x @ wqkv^T  -> bf16 (f16 MFMA)
  gemm_f16_bt<true><<<dim3(12, 64), 256, 0, stream>>>(x, wqkv, qkv_bf, nullptr, 8192, 1536, 512);

  // 2) fused conv1+IN+relu+conv2+IN+sigmoid -> w
  const int ldsC = 157440;
  hipFuncSetAttribute(reinterpret_cast<const void*>(&conv_fused3),
                      hipFuncAttributeMaxDynamicSharedMemorySize, ldsC);
  conv_fused3<<<1024, 1024, ldsC, stream>>>(rpe, w1frag, w2frag, g1w, g1b, g2w, g2b, wppe);

  // 3) fused attention
  attn_kernel<<<dim3(16, 64), 256, 0, stream>>>(qkv_bf, wppe, ohb);

  // 4) out = oh @ wproj^T + bproj (f16 MFMA)
  gemm_f16_bt<false><<<dim3(4, 64), 256, 0, stream>>>(ohb, wproj, out, bproj, 8192, 512, 512);
}